// Round 17
// baseline (18.632 us; speedup 1.0000x reference)
//
#include <hip/hip_runtime.h>

// Problem constants: V=50000, F=100000, H=W=256, K=1, B=4, J=256
#define NPIX  65536
#define BB    4
#define JJ    256

// Output layout (concatenated flat, fp32):
//   colors  : (B,H,W,3)  base 0
//   diffuse : (B,H,W,3)  base 786432
//   texels  : (1,H,W,3)  base 1572864
//   normals : (B,H,W,3)  base 1769472

struct F3 { float x, y, z; };
struct I3 { int x, y, z; };
typedef float f2 __attribute__((ext_vector_type(2)));

// Grid: 2048 blocks x 256 threads (R6's best-performing shape).
//   b = blockIdx>>9 (batch), pbase = (blockIdx&511)*128.
// Wave w -> light quarter jq (readfirstlane-pinned). Lane i owns the px pair
// {pbase+i, pbase+64+i} packed as <2 x float>.
// J-loop: lights read as float4 CHUNKS (6 dwordx4 per 4 lights = 4x fewer
// load instrs / L1 transactions than the scalar kernels), light components
// consumed as scalar SPLATS in v_pk_* ops (7 packed instrs / light / 2 px).
// fp32 exact throughout -> absmax identical to scalar baseline.
__global__ __launch_bounds__(256, 4) void shade_kernel(
    const int*   __restrict__ p2f,    // (1,H,W,1) int32
    const float* __restrict__ bary,   // (1,H,W,1,3)
    const int*   __restrict__ faces,  // (F,3)
    const float* __restrict__ vnorm,  // (V,3)
    const float* __restrict__ dirs,   // (B,J,3)
    const float* __restrict__ env,    // (B,J,3)
    const float* __restrict__ tex,    // (1,H,W,3)
    float*       __restrict__ out)
{
    const int b     = blockIdx.x >> 9;                 // batch (block-uniform)
    const int pbase = (blockIdx.x & 511) << 7;         // 128 px per block
    const int t     = threadIdx.x;
    const int i     = t & 63;                          // lane
    const int w     = t >> 6;                          // wave 0..3
    const int jq    = __builtin_amdgcn_readfirstlane(w);  // light quarter (SGPR)

    __shared__ float4 nlds[128];                       // 2 KB normals
    __shared__ f2     part[4][64][3];                  // 6 KB partials (f2 = pxA,pxB)

    const F3* __restrict__ bary3  = (const F3*)bary;
    const I3* __restrict__ faces3 = (const I3*)faces;
    const F3* __restrict__ vn3    = (const F3*)vnorm;
    const F3* __restrict__ tex3   = (const F3*)tex;

    // ---- Phase 1: threads 0..127 gather + normalize (once per pixel) ----
    if (t < 128) {
        const int p = pbase + t;
        const int f = p2f[p];
        const I3 vv = faces3[f];
        const F3 bc = bary3[p];
        const F3 a0 = vn3[vv.x];
        const F3 a1 = vn3[vv.y];
        const F3 a2 = vn3[vv.z];
        float nx = bc.x*a0.x + bc.y*a1.x + bc.z*a2.x;
        float ny = bc.x*a0.y + bc.y*a1.y + bc.z*a2.y;
        float nz = bc.x*a0.z + bc.y*a1.z + bc.z*a2.z;
        const float inv = 1.0f / fmaxf(sqrtf(nx*nx + ny*ny + nz*nz), 1e-6f);
        nx *= inv; ny *= inv; nz *= inv;
        nlds[t] = make_float4(nx, ny, nz, 0.f);

        // normals output (this block's batch copy)
        float* __restrict__ nor = out + (3*BB*NPIX*2 + 3*NPIX);
        const int o = 3*(b*NPIX + p);
        nor[o+0] = nx; nor[o+1] = ny; nor[o+2] = nz;

        // texels passthrough (batch-0 blocks cover all pixels)
        if (b == 0) {
            const F3 tv = tex3[p];
            float* __restrict__ tx = out + 3*BB*NPIX*2;
            tx[3*p+0] = tv.x; tx[3*p+1] = tv.y; tx[3*p+2] = tv.z;
        }
    }
    __syncthreads();

    // ---- Phase 2: 64 lights for quarter jq; 2 px/lane packed f32 ----
    const float4 nA = nlds[i];                         // px pbase+i
    const float4 nB = nlds[64 + i];                    // px pbase+64+i
    const f2 nx2 = {nA.x, nB.x};
    const f2 ny2 = {nA.y, nB.y};
    const f2 nz2 = {nA.z, nB.z};
    f2 ar2 = {0.f, 0.f}, ag2 = {0.f, 0.f}, ab2 = {0.f, 0.f};

    // (b*256 + jq*64)*3 floats is a multiple of 4 -> float4 cast is aligned
    const float4* __restrict__ d4 = (const float4*)(dirs + (b*JJ + jq*64)*3);
    const float4* __restrict__ e4 = (const float4*)(env  + (b*JJ + jq*64)*3);

#define LIGHT1(dx,dy,dz,er,eg,eb) {                                     \
    f2 wv = nx2 * (f2){dx, dx};                                         \
    wv = __builtin_elementwise_fma(ny2, (f2){dy, dy}, wv);              \
    wv = __builtin_elementwise_fma(nz2, (f2){dz, dz}, wv);              \
    wv = __builtin_elementwise_max(wv, (f2){0.f, 0.f});  /* dot<=1 */   \
    ar2 = __builtin_elementwise_fma((f2){er, er}, wv, ar2);             \
    ag2 = __builtin_elementwise_fma((f2){eg, eg}, wv, ag2);             \
    ab2 = __builtin_elementwise_fma((f2){eb, eb}, wv, ab2); }

    #pragma unroll 4
    for (int ch = 0; ch < 16; ++ch) {                  // 4 lights per chunk
        const float4 D0 = d4[ch*3 + 0];                // dx0 dy0 dz0 dx1
        const float4 D1 = d4[ch*3 + 1];                // dy1 dz1 dx2 dy2
        const float4 D2 = d4[ch*3 + 2];                // dz2 dx3 dy3 dz3
        const float4 E0 = e4[ch*3 + 0];
        const float4 E1 = e4[ch*3 + 1];
        const float4 E2 = e4[ch*3 + 2];
        LIGHT1(D0.x, D0.y, D0.z,  E0.x, E0.y, E0.z)
        LIGHT1(D0.w, D1.x, D1.y,  E0.w, E1.x, E1.y)
        LIGHT1(D1.z, D1.w, D2.x,  E1.z, E1.w, E2.x)
        LIGHT1(D2.y, D2.z, D2.w,  E2.y, E2.z, E2.w)
    }
#undef LIGHT1

    // ---- Phase 3: partials -> LDS ----
    part[w][i][0] = ar2;
    part[w][i][1] = ag2;
    part[w][i][2] = ab2;
    __syncthreads();

    // ---- Phase 4: threads 0..127 reduce quarters, write colors+diffuse ----
    if (t < 128) {
        const int ls = t & 63;                         // lane slot
        const int e  = t >> 6;                         // f2 element (0=pxA,1=pxB)
        const float sr = part[0][ls][0][e] + part[1][ls][0][e]
                       + part[2][ls][0][e] + part[3][ls][0][e];
        const float sg = part[0][ls][1][e] + part[1][ls][1][e]
                       + part[2][ls][1][e] + part[3][ls][1][e];
        const float sb = part[0][ls][2][e] + part[1][ls][2][e]
                       + part[2][ls][2][e] + part[3][ls][2][e];

        const int p = pbase + (e << 6) + ls;
        const F3 tv = tex3[p];
        const int o = 3*(b*NPIX + p);
        out[o+0] = sr*tv.x; out[o+1] = sg*tv.y; out[o+2] = sb*tv.z;

        float* __restrict__ dif = out + 3*BB*NPIX;
        dif[o+0] = sr; dif[o+1] = sg; dif[o+2] = sb;
    }
}

extern "C" void kernel_launch(void* const* d_in, const int* in_sizes, int n_in,
                              void* d_out, int out_size, void* d_ws, size_t ws_size,
                              hipStream_t stream) {
    const int*   p2f   = (const int*)  d_in[0];
    const float* bary  = (const float*)d_in[1];
    const int*   faces = (const int*)  d_in[2];
    // d_in[3] = verts (unused)
    const float* vnorm = (const float*)d_in[4];
    const float* dirs  = (const float*)d_in[5];
    const float* env   = (const float*)d_in[6];
    const float* tex   = (const float*)d_in[7];
    float* out = (float*)d_out;

    const int grid = BB * (NPIX / 128);   // 4 * 512 = 2048 blocks
    shade_kernel<<<grid, 256, 0, stream>>>(
        p2f, bary, faces, vnorm, dirs, env, tex, out);
}

// Round 18
// 17.531 us; speedup vs baseline: 1.0628x; 1.0628x over previous
//
#include <hip/hip_runtime.h>

// Problem constants: V=50000, F=100000, H=W=256, K=1, B=4, J=256
#define NPIX  65536
#define BB    4
#define JJ    256

// Output layout (concatenated flat, fp32):
//   colors  : (B,H,W,3)  base 0
//   diffuse : (B,H,W,3)  base 786432
//   texels  : (1,H,W,3)  base 1572864
//   normals : (B,H,W,3)  base 1769472

struct F3 { float x, y, z; };
struct I3 { int x, y, z; };
typedef float f2 __attribute__((ext_vector_type(2)));

// R13 geometry (best: 17.54us), single change: J-loop light loads are
// float4 chunks (6 dwordx4 / 4 lights) instead of 6 scalar dwords / light.
// Grid: 512 blocks x 1024 threads (16 waves/block; 8192 waves = 8/SIMD).
// Wave w: b = w>>2, jq = w&3 (readfirstlane-pinned). Lane L packs pixels
// (pbase+L, pbase+64+L) as <2 x float>; 7 v_pk_* per light per 2 px.
__global__ __launch_bounds__(1024, 8) void shade_kernel(
    const int*   __restrict__ p2f,    // (1,H,W,1) int32
    const float* __restrict__ bary,   // (1,H,W,1,3)
    const int*   __restrict__ faces,  // (F,3)
    const float* __restrict__ vnorm,  // (V,3)
    const float* __restrict__ dirs,   // (B,J,3)
    const float* __restrict__ env,    // (B,J,3)
    const float* __restrict__ tex,    // (1,H,W,3)
    float*       __restrict__ out)
{
    const int t     = threadIdx.x;
    const int L     = t & 63;                                   // lane
    const int jq    = __builtin_amdgcn_readfirstlane((t >> 6) & 3);  // light quarter
    const int b     = __builtin_amdgcn_readfirstlane(t >> 8);        // batch
    const int pbase = blockIdx.x << 7;                          // 128 px/block

    __shared__ float4 nlds[128];                                // 2 KB normals
    __shared__ f2     part[4][4][64][3];                        // 24 KB partials

    const F3* __restrict__ bary3  = (const F3*)bary;
    const I3* __restrict__ faces3 = (const I3*)faces;
    const F3* __restrict__ vn3    = (const F3*)vnorm;
    const F3* __restrict__ tex3   = (const F3*)tex;

    // ---- Phase 1: threads 0..127 gather + normalize (once per pixel) ----
    if (t < 128) {
        const int p = pbase + t;
        const int f = p2f[p];
        const I3 vv = faces3[f];
        const F3 bc = bary3[p];
        const F3 a0 = vn3[vv.x];
        const F3 a1 = vn3[vv.y];
        const F3 a2 = vn3[vv.z];
        float nx = bc.x*a0.x + bc.y*a1.x + bc.z*a2.x;
        float ny = bc.x*a0.y + bc.y*a1.y + bc.z*a2.y;
        float nz = bc.x*a0.z + bc.y*a1.z + bc.z*a2.z;
        const float inv = 1.0f / fmaxf(sqrtf(nx*nx + ny*ny + nz*nz), 1e-6f);
        nx *= inv; ny *= inv; nz *= inv;
        nlds[t] = make_float4(nx, ny, nz, 0.f);
    }
    __syncthreads();

    // ---- Phase 2: 64 lights for (b,jq); 2 px/lane, packed f32, chunked loads ----
    const float4 nA = nlds[L];                                  // pixel pbase+L
    const float4 nB = nlds[64 + L];                             // pixel pbase+64+L
    const f2 nx = {nA.x, nB.x};
    const f2 ny = {nA.y, nB.y};
    const f2 nz = {nA.z, nB.z};
    f2 ar = {0.f, 0.f}, ag = {0.f, 0.f}, ab = {0.f, 0.f};

    // (b*256 + jq*64)*3*4 bytes is 16B-aligned
    const float4* __restrict__ d4 = (const float4*)(dirs + (b*JJ + jq*64)*3);
    const float4* __restrict__ e4 = (const float4*)(env  + (b*JJ + jq*64)*3);

#define LIGHT1(dx,dy,dz,er,eg,eb) {                                     \
    f2 wv = nx * (f2){dx, dx};                                          \
    wv = __builtin_elementwise_fma(ny, (f2){dy, dy}, wv);               \
    wv = __builtin_elementwise_fma(nz, (f2){dz, dz}, wv);               \
    wv = __builtin_elementwise_max(wv, (f2){0.f, 0.f});  /* dot<=1 */   \
    ar = __builtin_elementwise_fma((f2){er, er}, wv, ar);               \
    ag = __builtin_elementwise_fma((f2){eg, eg}, wv, ag);               \
    ab = __builtin_elementwise_fma((f2){eb, eb}, wv, ab); }

    #pragma unroll 2
    for (int ch = 0; ch < 16; ++ch) {                  // 4 lights per chunk
        const float4 D0 = d4[ch*3 + 0];                // dx0 dy0 dz0 dx1
        const float4 D1 = d4[ch*3 + 1];                // dy1 dz1 dx2 dy2
        const float4 D2 = d4[ch*3 + 2];                // dz2 dx3 dy3 dz3
        const float4 E0 = e4[ch*3 + 0];
        const float4 E1 = e4[ch*3 + 1];
        const float4 E2 = e4[ch*3 + 2];
        LIGHT1(D0.x, D0.y, D0.z,  E0.x, E0.y, E0.z)
        LIGHT1(D0.w, D1.x, D1.y,  E0.w, E1.x, E1.y)
        LIGHT1(D1.z, D1.w, D2.x,  E1.z, E1.w, E2.x)
        LIGHT1(D2.y, D2.z, D2.w,  E2.y, E2.z, E2.w)
    }
#undef LIGHT1

    // ---- Phase 3: jq!=0 publish partials; jq==1 normals; (jq==2,b==0) texels ----
    if (jq != 0) {
        part[jq][b][L][0] = ar;
        part[jq][b][L][1] = ag;
        part[jq][b][L][2] = ab;
    }
    if (jq == 1) {                                              // normals, batch b
        float* __restrict__ nor = out + (3*BB*NPIX*2 + 3*NPIX);
        const int pA = pbase + L, pB = pbase + 64 + L;
        const int oA = 3*(b*NPIX + pA), oB = 3*(b*NPIX + pB);
        nor[oA+0] = nA.x; nor[oA+1] = nA.y; nor[oA+2] = nA.z;
        nor[oB+0] = nB.x; nor[oB+1] = nB.y; nor[oB+2] = nB.z;
    }
    if (jq == 2 && b == 0) {                                    // texels passthrough
        float* __restrict__ tx = out + 3*BB*NPIX*2;
        const int pA = pbase + L, pB = pbase + 64 + L;
        const F3 tA = tex3[pA], tB = tex3[pB];
        tx[3*pA+0] = tA.x; tx[3*pA+1] = tA.y; tx[3*pA+2] = tA.z;
        tx[3*pB+0] = tB.x; tx[3*pB+1] = tB.y; tx[3*pB+2] = tB.z;
    }
    __syncthreads();

    // ---- Phase 4: jq==0 waves reduce quarters + store colors/diffuse ----
    if (jq == 0) {
        f2 sr = ar, sg = ag, sb = ab;
        #pragma unroll
        for (int q = 1; q < 4; ++q) {
            sr += part[q][b][L][0];
            sg += part[q][b][L][1];
            sb += part[q][b][L][2];
        }
        const int pA = pbase + L, pB = pbase + 64 + L;
        const F3 tA = tex3[pA], tB = tex3[pB];
        const int oA = 3*(b*NPIX + pA), oB = 3*(b*NPIX + pB);

        out[oA+0] = sr.x*tA.x; out[oA+1] = sg.x*tA.y; out[oA+2] = sb.x*tA.z;
        out[oB+0] = sr.y*tB.x; out[oB+1] = sg.y*tB.y; out[oB+2] = sb.y*tB.z;

        float* __restrict__ dif = out + 3*BB*NPIX;
        dif[oA+0] = sr.x; dif[oA+1] = sg.x; dif[oA+2] = sb.x;
        dif[oB+0] = sr.y; dif[oB+1] = sg.y; dif[oB+2] = sb.y;
    }
}

extern "C" void kernel_launch(void* const* d_in, const int* in_sizes, int n_in,
                              void* d_out, int out_size, void* d_ws, size_t ws_size,
                              hipStream_t stream) {
    const int*   p2f   = (const int*)  d_in[0];
    const float* bary  = (const float*)d_in[1];
    const int*   faces = (const int*)  d_in[2];
    // d_in[3] = verts (unused)
    const float* vnorm = (const float*)d_in[4];
    const float* dirs  = (const float*)d_in[5];
    const float* env   = (const float*)d_in[6];
    const float* tex   = (const float*)d_in[7];
    float* out = (float*)d_out;

    const int grid = NPIX / 128;            // 512 blocks x 1024 threads
    shade_kernel<<<grid, 1024, 0, stream>>>(
        p2f, bary, faces, vnorm, dirs, env, tex, out);
}